// Round 1
// baseline (294.514 us; speedup 1.0000x reference)
//
#include <hip/hip_runtime.h>
#include <stdint.h>
#include <stddef.h>

// Problem constants
#define B_N   4096
#define NSENT 64
#define DDIM  768
#define TOPK  5
#define FAN1  4608   // (TOPK+1)*768
#define H1DIM 1024
#define NCLS  4
#define KDIM  4608

typedef __attribute__((ext_vector_type(8))) __bf16 bf16x8;
typedef __attribute__((ext_vector_type(4))) float  f32x4;

__device__ __forceinline__ unsigned short f2bf(float f) {
    unsigned int u = __float_as_uint(f);
    unsigned int r = (u + 0x7fffu + ((u >> 16) & 1u)) >> 16;
    return (unsigned short)r;
}

__device__ __forceinline__ void gl_lds16(const void* g, void* l) {
    __builtin_amdgcn_global_load_lds((__attribute__((address_space(1))) void*)(g),
                                     (__attribute__((address_space(3))) void*)(l),
                                     16, 0, 0);
}

// ---------------------------------------------------------------------------
// Kernel A: per batch row b: sims[n] = <sim_stance[b], sim_body[b,n]> (f32),
// top-5 (desc, ties -> lower index, matching jax.lax.top_k), then gather
// nli_stance + 5 nli_body rows -> xx[b] as bf16 (4608 elems).
// ---------------------------------------------------------------------------
__global__ __launch_bounds__(256) void k_topk_gather(
    const float* __restrict__ sim_stance,
    const float* __restrict__ sim_body,
    const float* __restrict__ nli_stance,
    const float* __restrict__ nli_body,
    unsigned short* __restrict__ xx)
{
    const int b    = blockIdx.x;
    const int tid  = threadIdx.x;
    const int lane = tid & 63;
    const int wave = tid >> 6;
    __shared__ float sims[NSENT];
    __shared__ int   topidx[TOPK];

    // per-lane stance fragment: elements (j*64+lane)*4 .. +3, j = 0..2
    const float4* st4 = (const float4*)(sim_stance + (size_t)b * DDIM);
    const float4  s0 = st4[lane], s1 = st4[64 + lane], s2 = st4[128 + lane];

    const float* bodyb = sim_body + (size_t)b * NSENT * DDIM;
    for (int n = wave; n < NSENT; n += 4) {
        const float4* r4 = (const float4*)(bodyb + (size_t)n * DDIM);
        float4 a = r4[lane], c = r4[64 + lane], e = r4[128 + lane];
        float p = a.x*s0.x + a.y*s0.y + a.z*s0.z + a.w*s0.w
                + c.x*s1.x + c.y*s1.y + c.z*s1.z + c.w*s1.w
                + e.x*s2.x + e.y*s2.y + e.z*s2.z + e.w*s2.w;
        #pragma unroll
        for (int off = 32; off; off >>= 1) p += __shfl_xor(p, off);
        if (lane == 0) sims[n] = p;
    }
    __syncthreads();

    // wave 0: 5x butterfly argmax (strict >, tie -> lower index)
    if (wave == 0) {
        float v = sims[lane];
        #pragma unroll
        for (int k = 0; k < TOPK; ++k) {
            float bv = v; int bi = lane;
            #pragma unroll
            for (int off = 32; off; off >>= 1) {
                float ov = __shfl_xor(bv, off);
                int   oi = __shfl_xor(bi, off);
                if (ov > bv || (ov == bv && oi < bi)) { bv = ov; bi = oi; }
            }
            if (lane == 0) topidx[k] = bi;
            if (lane == bi) v = -3.402823466e38f;
        }
    }
    __syncthreads();

    // gather + f32->bf16 convert: 6 segments of 768 (= 192 float4 each)
    unsigned short* xrow = xx + (size_t)b * FAN1;
    if (tid < 192) {
        #pragma unroll
        for (int seg = 0; seg < 6; ++seg) {
            const float* src = (seg == 0)
                ? (nli_stance + (size_t)b * DDIM)
                : (nli_body + ((size_t)b * NSENT + topidx[seg - 1]) * DDIM);
            float4 v = ((const float4*)src)[tid];
            ushort4 o;
            o.x = f2bf(v.x); o.y = f2bf(v.y); o.z = f2bf(v.z); o.w = f2bf(v.w);
            ((ushort4*)(xrow + seg * DDIM))[tid] = o;
        }
    }
}

// ---------------------------------------------------------------------------
// W1 f32 -> bf16 (row-major [H1][FAN1] preserved; acts as B^T for the GEMM)
// ---------------------------------------------------------------------------
__global__ __launch_bounds__(256) void k_f32_to_bf16x4(
    const float* __restrict__ in, unsigned short* __restrict__ o, int n4)
{
    int i = blockIdx.x * 256 + threadIdx.x;
    if (i < n4) {
        float4 v = ((const float4*)in)[i];
        ushort4 r;
        r.x = f2bf(v.x); r.y = f2bf(v.y); r.z = f2bf(v.z); r.w = f2bf(v.w);
        ((ushort4*)o)[i] = r;
    }
}

// ---------------------------------------------------------------------------
// GEMM1: hidden[m][h] = relu( sum_k xx[m][k]*W1[h][k] + b1[h] )
// M=4096 N=1024 K=4608, bf16 MFMA 16x16x32, BM=128 BN=64 BK=32,
// 4 waves (2x2), wave tile 64x32 (4x2 fragments), global_load_lds staging.
// ---------------------------------------------------------------------------
__global__ __launch_bounds__(256, 2) void k_gemm1(
    const unsigned short* __restrict__ A,   // xx bf16 [4096][4608]
    const unsigned short* __restrict__ W,   // W1 bf16 [1024][4608]
    const float* __restrict__ bias,
    float* __restrict__ Hd)                 // [4096][1024] f32
{
    constexpr int BM = 128, BN = 64, BK = 32;
    constexpr int K = KDIM;
    __shared__ unsigned short lA[BM * BK];  // row-major, 32 elems (64B) per row
    __shared__ unsigned short lB[BN * BK];

    const int tid = threadIdx.x, lane = tid & 63, wave = tid >> 6;
    const int bn = blockIdx.x & 15, bm = blockIdx.x >> 4;
    const int wm = wave >> 1, wn = wave & 1;

    // staging: chunk q covers LDS elements [q*8, q*8+8) = row q/4, cols (q&3)*8..
    const int qA0 = wave * 128 + lane;      // A chunks: 512 total, 2 per thread
    const int qA1 = qA0 + 64;
    const int qB  = wave * 64 + lane;       // B chunks: 256 total, 1 per thread
    const unsigned short* gA0 = A + (size_t)(bm * BM + (qA0 >> 2)) * K + (qA0 & 3) * 8;
    const unsigned short* gA1 = A + (size_t)(bm * BM + (qA1 >> 2)) * K + (qA1 & 3) * 8;
    const unsigned short* gB0 = W + (size_t)(bn * BN + (qB  >> 2)) * K + (qB  & 3) * 8;
    unsigned short* lAd0 = &lA[(wave * 2 + 0) * 512];   // wave-uniform dest
    unsigned short* lAd1 = &lA[(wave * 2 + 1) * 512];
    unsigned short* lBd  = &lB[wave * 512];

    const int r16 = lane & 15, kh = (lane >> 4) * 8;
    const unsigned short* pa = &lA[(wm * 64 + r16) * BK + kh];
    const unsigned short* pb = &lB[(wn * 32 + r16) * BK + kh];

    f32x4 acc[4][2];
    #pragma unroll
    for (int m = 0; m < 4; ++m)
        #pragma unroll
        for (int n = 0; n < 2; ++n) acc[m][n] = {0.f, 0.f, 0.f, 0.f};

    for (int kt = 0; kt < K / BK; ++kt) {
        gl_lds16(gA0, lAd0);
        gl_lds16(gA1, lAd1);
        gl_lds16(gB0, lBd);
        gA0 += BK; gA1 += BK; gB0 += BK;
        __syncthreads();   // compiler emits vmcnt(0) drain before barrier

        bf16x8 fa[4], fb[2];
        #pragma unroll
        for (int m = 0; m < 4; ++m) fa[m] = *(const bf16x8*)(pa + m * 16 * BK);
        #pragma unroll
        for (int n = 0; n < 2; ++n) fb[n] = *(const bf16x8*)(pb + n * 16 * BK);
        #pragma unroll
        for (int m = 0; m < 4; ++m)
            #pragma unroll
            for (int n = 0; n < 2; ++n)
                acc[m][n] = __builtin_amdgcn_mfma_f32_16x16x32_bf16(fa[m], fb[n], acc[m][n], 0, 0, 0);
        __syncthreads();
    }

    // epilogue: C/D layout col=lane&15, row=(lane>>4)*4+reg
    const int colbase = bn * BN + wn * 32 + r16;
    const int rowbase = bm * BM + wm * 64 + (lane >> 4) * 4;
    #pragma unroll
    for (int n = 0; n < 2; ++n) {
        const int col = colbase + n * 16;
        const float bv = bias[col];
        #pragma unroll
        for (int m = 0; m < 4; ++m) {
            const int row = rowbase + m * 16;
            #pragma unroll
            for (int j = 0; j < 4; ++j) {
                float x = acc[m][n][j] + bv;
                Hd[(size_t)(row + j) * H1DIM + col] = x > 0.f ? x : 0.f;
            }
        }
    }
}

// ---------------------------------------------------------------------------
// GEMM2: out[b][c] = sum_h hidden[b][h]*W2[c][h] + b2[c]; one wave per row.
// ---------------------------------------------------------------------------
__global__ __launch_bounds__(256) void k_gemm2(
    const float* __restrict__ Hd, const float* __restrict__ W2,
    const float* __restrict__ b2, float* __restrict__ out)
{
    __shared__ float w2s[NCLS * H1DIM];
    const int tid = threadIdx.x, lane = tid & 63, wave = tid >> 6;
    const int row = blockIdx.x * 4 + wave;
    for (int i = tid; i < NCLS * H1DIM; i += 256) w2s[i] = W2[i];
    __syncthreads();

    const float4* h4 = (const float4*)(Hd + (size_t)row * H1DIM);
    const float4* w0 = (const float4*)&w2s[0];
    const float4* w1 = (const float4*)&w2s[H1DIM];
    const float4* w2 = (const float4*)&w2s[2 * H1DIM];
    const float4* w3 = (const float4*)&w2s[3 * H1DIM];
    float a0 = 0.f, a1 = 0.f, a2 = 0.f, a3 = 0.f;
    #pragma unroll
    for (int j = 0; j < 4; ++j) {
        const int idx = j * 64 + lane;
        float4 h = h4[idx], x;
        x = w0[idx]; a0 += h.x*x.x + h.y*x.y + h.z*x.z + h.w*x.w;
        x = w1[idx]; a1 += h.x*x.x + h.y*x.y + h.z*x.z + h.w*x.w;
        x = w2[idx]; a2 += h.x*x.x + h.y*x.y + h.z*x.z + h.w*x.w;
        x = w3[idx]; a3 += h.x*x.x + h.y*x.y + h.z*x.z + h.w*x.w;
    }
    #pragma unroll
    for (int off = 32; off; off >>= 1) {
        a0 += __shfl_xor(a0, off);
        a1 += __shfl_xor(a1, off);
        a2 += __shfl_xor(a2, off);
        a3 += __shfl_xor(a3, off);
    }
    if (lane == 0) {
        float* o = out + (size_t)row * NCLS;
        o[0] = a0 + b2[0]; o[1] = a1 + b2[1]; o[2] = a2 + b2[2]; o[3] = a3 + b2[3];
    }
}

// ---------------------------------------------------------------------------
// Workspace layout (bytes):
//   [0, 37748736)                 xx bf16      4096*4608*2
//   [37748736, 47185920)          W1 bf16      1024*4608*2
//   [47185920, 63963136)          hidden f32   4096*1024*4
// ---------------------------------------------------------------------------
extern "C" void kernel_launch(void* const* d_in, const int* in_sizes, int n_in,
                              void* d_out, int out_size, void* d_ws, size_t ws_size,
                              hipStream_t stream)
{
    const float* sim_stance = (const float*)d_in[0];
    const float* nli_stance = (const float*)d_in[1];
    const float* sim_body   = (const float*)d_in[2];
    const float* nli_body   = (const float*)d_in[3];
    const float* W1 = (const float*)d_in[4];
    const float* b1 = (const float*)d_in[5];
    const float* W2 = (const float*)d_in[6];
    const float* b2 = (const float*)d_in[7];
    float* out = (float*)d_out;

    char* ws = (char*)d_ws;
    unsigned short* xx     = (unsigned short*)ws;
    unsigned short* w1b    = (unsigned short*)(ws + 37748736u);
    float*          hidden = (float*)(ws + 37748736u + 9437184u);

    k_f32_to_bf16x4<<<dim3(4608), dim3(256), 0, stream>>>(W1, w1b, 1179648);
    k_topk_gather<<<dim3(B_N), dim3(256), 0, stream>>>(sim_stance, sim_body,
                                                       nli_stance, nli_body, xx);
    k_gemm1<<<dim3(512), dim3(256), 0, stream>>>(xx, w1b, b1, hidden);
    k_gemm2<<<dim3(1024), dim3(256), 0, stream>>>(hidden, W2, b2, out);
}

// Round 3
// 277.248 us; speedup vs baseline: 1.0623x; 1.0623x over previous
//
#include <hip/hip_runtime.h>
#include <stdint.h>
#include <stddef.h>

// Problem constants
#define B_N   4096
#define NSENT 64
#define DDIM  768
#define TOPK  5
#define FAN1  4608   // (TOPK+1)*768
#define H1DIM 1024
#define NCLS  4
#define KDIM  4608

typedef __attribute__((ext_vector_type(8))) __bf16 bf16x8;
typedef __attribute__((ext_vector_type(4))) float  f32x4;

__device__ __forceinline__ unsigned short f2bf(float f) {
    unsigned int u = __float_as_uint(f);
    unsigned int r = (u + 0x7fffu + ((u >> 16) & 1u)) >> 16;
    return (unsigned short)r;
}

__device__ __forceinline__ void gl_lds16(const void* g, void* l) {
    __builtin_amdgcn_global_load_lds((__attribute__((address_space(1))) void*)(g),
                                     (__attribute__((address_space(3))) void*)(l),
                                     16, 0, 0);
}

// ---------------------------------------------------------------------------
// Kernel A: per batch row b: sims[n] = <sim_stance[b], sim_body[b,n]> (f32),
// top-5 (desc, ties -> lower index, matching jax.lax.top_k), then gather
// nli_stance + 5 nli_body rows -> xx[b] as bf16 (4608 elems).
// ---------------------------------------------------------------------------
__global__ __launch_bounds__(256) void k_topk_gather(
    const float* __restrict__ sim_stance,
    const float* __restrict__ sim_body,
    const float* __restrict__ nli_stance,
    const float* __restrict__ nli_body,
    unsigned short* __restrict__ xx)
{
    const int b    = blockIdx.x;
    const int tid  = threadIdx.x;
    const int lane = tid & 63;
    const int wave = tid >> 6;
    __shared__ float sims[NSENT];
    __shared__ int   topidx[TOPK];

    // per-lane stance fragment: elements (j*64+lane)*4 .. +3, j = 0..2
    const float4* st4 = (const float4*)(sim_stance + (size_t)b * DDIM);
    const float4  s0 = st4[lane], s1 = st4[64 + lane], s2 = st4[128 + lane];

    const float* bodyb = sim_body + (size_t)b * NSENT * DDIM;
    for (int n = wave; n < NSENT; n += 4) {
        const float4* r4 = (const float4*)(bodyb + (size_t)n * DDIM);
        float4 a = r4[lane], c = r4[64 + lane], e = r4[128 + lane];
        float p = a.x*s0.x + a.y*s0.y + a.z*s0.z + a.w*s0.w
                + c.x*s1.x + c.y*s1.y + c.z*s1.z + c.w*s1.w
                + e.x*s2.x + e.y*s2.y + e.z*s2.z + e.w*s2.w;
        #pragma unroll
        for (int off = 32; off; off >>= 1) p += __shfl_xor(p, off);
        if (lane == 0) sims[n] = p;
    }
    __syncthreads();

    // wave 0: 5x butterfly argmax (strict >, tie -> lower index)
    if (wave == 0) {
        float v = sims[lane];
        #pragma unroll
        for (int k = 0; k < TOPK; ++k) {
            float bv = v; int bi = lane;
            #pragma unroll
            for (int off = 32; off; off >>= 1) {
                float ov = __shfl_xor(bv, off);
                int   oi = __shfl_xor(bi, off);
                if (ov > bv || (ov == bv && oi < bi)) { bv = ov; bi = oi; }
            }
            if (lane == 0) topidx[k] = bi;
            if (lane == bi) v = -3.402823466e38f;
        }
    }
    __syncthreads();

    // gather + f32->bf16 convert: 6 segments of 768 floats (192 float4 each)
    // = 1152 float4 tasks spread over all 256 threads.
    unsigned short* xrow = xx + (size_t)b * FAN1;
    for (int task = tid; task < 1152; task += 256) {
        const int seg = task / 192;
        const int t   = task - seg * 192;
        const float* src = (seg == 0)
            ? (nli_stance + (size_t)b * DDIM)
            : (nli_body + ((size_t)b * NSENT + topidx[seg - 1]) * DDIM);
        float4 v = ((const float4*)src)[t];
        ushort4 o;
        o.x = f2bf(v.x); o.y = f2bf(v.y); o.z = f2bf(v.z); o.w = f2bf(v.w);
        ((ushort4*)(xrow + seg * DDIM))[t] = o;
    }
}

// ---------------------------------------------------------------------------
// W1 f32 -> bf16 (row-major [H1][FAN1] preserved; acts as B^T for the GEMM)
// ---------------------------------------------------------------------------
__global__ __launch_bounds__(256) void k_f32_to_bf16x4(
    const float* __restrict__ in, unsigned short* __restrict__ o, int n4)
{
    int i = blockIdx.x * 256 + threadIdx.x;
    if (i < n4) {
        float4 v = ((const float4*)in)[i];
        ushort4 r;
        r.x = f2bf(v.x); r.y = f2bf(v.y); r.z = f2bf(v.z); r.w = f2bf(v.w);
        ((ushort4*)o)[i] = r;
    }
}

// ---------------------------------------------------------------------------
// GEMM1: hidden[m][h] = relu( sum_k xx[m][k]*W1[h][k] + b1[h] )
// M=4096 N=1024 K=4608, bf16 MFMA 16x16x32.
// BM=128 BN=64 BK=64, 4 waves (2m x 2n), wave tile 64x32, 16 MFMA / 3
// global_load_lds per wave per K-step.
// LDS chunk swizzle (both-sides involution, m173/m201 pattern): LDS is
// linear [rows][8 chunks of 8 bf16]; chunk slot c of row r holds global
// chunk (c ^ (r&7)). global_load_lds dest stays linear (wave-uniform base
// + lane*16); the per-lane GLOBAL source address applies the permutation;
// fragment ds_read applies the same XOR -> rows r / r+8 alias only (2-way,
// free), instead of 16-way conflicts on 128-B rows.
// ---------------------------------------------------------------------------
__global__ __launch_bounds__(256, 2) void k_gemm1(
    const unsigned short* __restrict__ A,   // xx bf16 [4096][4608]
    const unsigned short* __restrict__ W,   // W1 bf16 [1024][4608]
    const float* __restrict__ bias,
    float* __restrict__ Hd)                 // [4096][1024] f32
{
    constexpr int BM = 128, BN = 64, BK = 64;
    constexpr int K = KDIM;
    __shared__ unsigned short lA[BM * BK];  // 16 KB
    __shared__ unsigned short lB[BN * BK];  // 8 KB

    const int tid = threadIdx.x, lane = tid & 63, wave = tid >> 6;
    const int bn = blockIdx.x & 15, bm = blockIdx.x >> 4;
    const int wm = wave >> 1, wn = wave & 1;

    // ---- staging setup ----
    // chunk id within tile: q = j*256 + wave*64 + lane  (A: j=0..3, B: j=0..1)
    // row  = q>>3  (= j*32 + (q8 := wave*8 + (lane>>3)))
    // swizzled source col-chunk sc = (q&7) ^ (row&7); row&7 == q8&7 for all j.
    const int q   = wave * 64 + lane;
    const int q8  = q >> 3;              // row within 32-row group
    const int sc  = (q & 7) ^ (q8 & 7);  // swizzled global chunk-in-row
    const unsigned short* gA[4];
    const unsigned short* gB[2];
    #pragma unroll
    for (int j = 0; j < 4; ++j)
        gA[j] = A + (size_t)(bm * BM + j * 32 + q8) * K + sc * 8;
    #pragma unroll
    for (int j = 0; j < 2; ++j)
        gB[j] = W + (size_t)(bn * BN + j * 32 + q8) * K + sc * 8;
    unsigned short* lAd[4];
    unsigned short* lBd[2];
    #pragma unroll
    for (int j = 0; j < 4; ++j) lAd[j] = &lA[(j * 256 + wave * 64) * 8];
    #pragma unroll
    for (int j = 0; j < 2; ++j) lBd[j] = &lB[(j * 256 + wave * 64) * 8];

    // ---- fragment read setup (swizzled) ----
    const int r16 = lane & 15;
    const int x   = r16 & 7;
    const int p0  = (lane >> 4) ^ x;        // chunk slot for k-half 0
    const int p1  = p0 ^ 4;                 // chunk slot for k-half 1
    const unsigned short* paBase = &lA[(wm * 64 + r16) * BK];
    const unsigned short* pbBase = &lB[(wn * 32 + r16) * BK];

    f32x4 acc[4][2];
    #pragma unroll
    for (int m = 0; m < 4; ++m)
        #pragma unroll
        for (int n = 0; n < 2; ++n) acc[m][n] = {0.f, 0.f, 0.f, 0.f};

    for (int kt = 0; kt < K / BK; ++kt) {
        #pragma unroll
        for (int j = 0; j < 4; ++j) { gl_lds16(gA[j], lAd[j]); gA[j] += BK; }
        #pragma unroll
        for (int j = 0; j < 2; ++j) { gl_lds16(gB[j], lBd[j]); gB[j] += BK; }
        __syncthreads();   // compiler emits vmcnt(0) drain before barrier

        bf16x8 fa[4][2], fb[2][2];
        #pragma unroll
        for (int m = 0; m < 4; ++m) {
            fa[m][0] = *(const bf16x8*)(paBase + m * 16 * BK + p0 * 8);
            fa[m][1] = *(const bf16x8*)(paBase + m * 16 * BK + p1 * 8);
        }
        #pragma unroll
        for (int n = 0; n < 2; ++n) {
            fb[n][0] = *(const bf16x8*)(pbBase + n * 16 * BK + p0 * 8);
            fb[n][1] = *(const bf16x8*)(pbBase + n * 16 * BK + p1 * 8);
        }
        #pragma unroll
        for (int h = 0; h < 2; ++h)
            #pragma unroll
            for (int m = 0; m < 4; ++m)
                #pragma unroll
                for (int n = 0; n < 2; ++n)
                    acc[m][n] = __builtin_amdgcn_mfma_f32_16x16x32_bf16(
                        fa[m][h], fb[n][h], acc[m][n], 0, 0, 0);
        __syncthreads();
    }

    // epilogue: C/D layout col=lane&15, row=(lane>>4)*4+reg
    const int colbase = bn * BN + wn * 32 + r16;
    const int rowbase = bm * BM + wm * 64 + (lane >> 4) * 4;
    #pragma unroll
    for (int n = 0; n < 2; ++n) {
        const int col = colbase + n * 16;
        const float bv = bias[col];
        #pragma unroll
        for (int m = 0; m < 4; ++m) {
            const int row = rowbase + m * 16;
            #pragma unroll
            for (int j = 0; j < 4; ++j) {
                float v = acc[m][n][j] + bv;
                Hd[(size_t)(row + j) * H1DIM + col] = v > 0.f ? v : 0.f;
            }
        }
    }
}

// ---------------------------------------------------------------------------
// GEMM2: out[b][c] = sum_h hidden[b][h]*W2[c][h] + b2[c]; one wave per row.
// ---------------------------------------------------------------------------
__global__ __launch_bounds__(256) void k_gemm2(
    const float* __restrict__ Hd, const float* __restrict__ W2,
    const float* __restrict__ b2, float* __restrict__ out)
{
    __shared__ float w2s[NCLS * H1DIM];
    const int tid = threadIdx.x, lane = tid & 63, wave = tid >> 6;
    const int row = blockIdx.x * 4 + wave;
    for (int i = tid; i < NCLS * H1DIM; i += 256) w2s[i] = W2[i];
    __syncthreads();

    const float4* h4 = (const float4*)(Hd + (size_t)row * H1DIM);
    const float4* w0 = (const float4*)&w2s[0];
    const float4* w1 = (const float4*)&w2s[H1DIM];
    const float4* w2 = (const float4*)&w2s[2 * H1DIM];
    const float4* w3 = (const float4*)&w2s[3 * H1DIM];
    float a0 = 0.f, a1 = 0.f, a2 = 0.f, a3 = 0.f;
    #pragma unroll
    for (int j = 0; j < 4; ++j) {
        const int idx = j * 64 + lane;
        float4 h = h4[idx], xv;
        xv = w0[idx]; a0 += h.x*xv.x + h.y*xv.y + h.z*xv.z + h.w*xv.w;
        xv = w1[idx]; a1 += h.x*xv.x + h.y*xv.y + h.z*xv.z + h.w*xv.w;
        xv = w2[idx]; a2 += h.x*xv.x + h.y*xv.y + h.z*xv.z + h.w*xv.w;
        xv = w3[idx]; a3 += h.x*xv.x + h.y*xv.y + h.z*xv.z + h.w*xv.w;
    }
    #pragma unroll
    for (int off = 32; off; off >>= 1) {
        a0 += __shfl_xor(a0, off);
        a1 += __shfl_xor(a1, off);
        a2 += __shfl_xor(a2, off);
        a3 += __shfl_xor(a3, off);
    }
    if (lane == 0) {
        float* o = out + (size_t)row * NCLS;
        o[0] = a0 + b2[0]; o[1] = a1 + b2[1]; o[2] = a2 + b2[2]; o[3] = a3 + b2[3];
    }
}

// ---------------------------------------------------------------------------
// Workspace layout (bytes):
//   [0, 37748736)                 xx bf16      4096*4608*2
//   [37748736, 47185920)          W1 bf16      1024*4608*2
//   [47185920, 63963136)          hidden f32   4096*1024*4
// ---------------------------------------------------------------------------
extern "C" void kernel_launch(void* const* d_in, const int* in_sizes, int n_in,
                              void* d_out, int out_size, void* d_ws, size_t ws_size,
                              hipStream_t stream)
{
    const float* sim_stance = (const float*)d_in[0];
    const float* nli_stance = (const float*)d_in[1];
    const float* sim_body   = (const float*)d_in[2];
    const float* nli_body   = (const float*)d_in[3];
    const float* W1 = (const float*)d_in[4];
    const float* b1 = (const float*)d_in[5];
    const float* W2 = (const float*)d_in[6];
    const float* b2 = (const float*)d_in[7];
    float* out = (float*)d_out;

    char* ws = (char*)d_ws;
    unsigned short* xx     = (unsigned short*)ws;
    unsigned short* w1b    = (unsigned short*)(ws + 37748736u);
    float*          hidden = (float*)(ws + 37748736u + 9437184u);

    k_f32_to_bf16x4<<<dim3(4608), dim3(256), 0, stream>>>(W1, w1b, 1179648);
    k_topk_gather<<<dim3(B_N), dim3(256), 0, stream>>>(sim_stance, sim_body,
                                                       nli_stance, nli_body, xx);
    k_gemm1<<<dim3(512), dim3(256), 0, stream>>>(xx, w1b, b1, hidden);
    k_gemm2<<<dim3(1024), dim3(256), 0, stream>>>(hidden, W2, b2, out);
}